// Round 4
// baseline (606.073 us; speedup 1.0000x reference)
//
#include <hip/hip_runtime.h>
#include <hip/hip_bf16.h>
#include <math.h>

#define B_   4
#define C_   192
#define N_   6400
#define K_   9
#define M_   50
#define TK_  12
#define OC_  192
#define KC_  576     // 3*C
#define CH_  100     // one partial slice per fused logits block (64 points)
#define LSTR 53      // padded lg row stride (fp32; odd -> conflict-free)
#define GSTR 40      // bf16 LDS row stride (80 B, 16B-aligned, 2-way -> free)

typedef __bf16 b16x8 __attribute__((ext_vector_type(8)));
typedef float f32x4 __attribute__((ext_vector_type(4)));

__device__ inline unsigned short f2b(float f) {
    union { __hip_bfloat16 h; unsigned short u; } v;
    v.h = __float2bfloat16(f);
    return v.u;
}
__device__ inline float b2f(unsigned short u) {
    union { float f; unsigned int i; } v;
    v.i = ((unsigned int)u) << 16;
    return v.f;
}

// ---------------- W re-permute -> bf16: Wg16[o][t*192+ch] = conv_w[o][ch*3+t]
__global__ void k_rearrange_w(const float* __restrict__ cw, unsigned short* __restrict__ Wg16) {
    int g = blockIdx.x * 256 + threadIdx.x;           // < 192*576
    int o = g / KC_, r = g % KC_;
    int t = r / C_, ch = r % C_;
    Wg16[g] = f2b(cw[o * KC_ + ch * 3 + t]);
}

// ---------------- transpose x (b,c,n) -> xt fp32 + xt16 bf16 (b,n,c) ---------
__global__ void k_transpose(const float* __restrict__ x, float* __restrict__ xt,
                            unsigned short* __restrict__ xt16) {
    __shared__ float tile[32][33];
    int b = blockIdx.z;
    int p0 = blockIdx.x * 32, c0 = blockIdx.y * 32;
    int tx = threadIdx.x, ty = threadIdx.y;
    const float* xb = x + (size_t)b * C_ * N_;
    float* xtb = xt + (size_t)b * N_ * C_;
    unsigned short* xt16b = xt16 + (size_t)b * N_ * C_;
#pragma unroll
    for (int i = 0; i < 4; i++) {
        int cc = ty + 8 * i;
        tile[cc][tx] = xb[(size_t)(c0 + cc) * N_ + p0 + tx];
    }
    __syncthreads();
#pragma unroll
    for (int i = 0; i < 4; i++) {
        int pp = ty + 8 * i;
        float v = tile[tx][pp];
        size_t o = (size_t)(p0 + pp) * C_ + c0 + tx;
        xtb[o] = v;
        xt16b[o] = f2b(v);
    }
}

// ---------------- initial centroids: 5x10 adaptive avg pool (+ |c|^2) --------
__global__ __launch_bounds__(192) void k_init_cent(const float* __restrict__ xt,
        float* __restrict__ cent, float* __restrict__ c2) {
    int m = blockIdx.x, b = blockIdx.y, c = threadIdx.x;
    int gy = m / 10, gx = m % 10;
    const float* xtb = xt + (size_t)b * N_ * C_;
    float s = 0.f;
    for (int yy = 0; yy < 16; yy++)
        for (int xx = 0; xx < 8; xx++) {
            int p = (gy * 16 + yy) * 80 + gx * 8 + xx;
            s += xtb[(size_t)p * C_ + c];
        }
    float v = s * (1.f / 128.f);
    cent[((size_t)b * M_ + m) * C_ + c] = v;
    float q = v * v;
    __shared__ float red[3];
#pragma unroll
    for (int off = 32; off > 0; off >>= 1) q += __shfl_down(q, off, 64);
    if ((c & 63) == 0) red[c >> 6] = q;
    __syncthreads();
    if (c == 0) c2[(size_t)b * M_ + m] = red[0] + red[1] + red[2];
}

// ---- fused: logits GEMM + softmax + centroid-update partial GEMM (+ topk) ---
// block = 64 points. phase 1: lg[p][m] = softmax(2*x.c - |c|^2).
// phase 2: part[m][c] = sum_p w[p][m]*x[p][c]  (same outer-product micro-kernel)
__global__ __launch_bounds__(256) void k_logits_upd(const float* __restrict__ xt,
        const float* __restrict__ cent, const float* __restrict__ c2g,
        float* __restrict__ part, float* __restrict__ wsp,
        int* __restrict__ nn, int do_topk) {
    __shared__ float Ac[16][68];
    __shared__ float Bp[16][68];
    __shared__ float lg[64 * LSTR];
    __shared__ float sred[256];
    int b = blockIdx.y;
    int blk = blockIdx.x;
    int p0 = blk * 64;
    int tid = threadIdx.x;
    int tx = tid & 15, ty = tid >> 4;
    int lr = tid >> 2, lq = tid & 3;
    const float* cb = cent + (size_t)b * M_ * C_;
    const float* xb = xt + ((size_t)b * N_ + p0) * C_;
    // ---- phase 1: logits GEMM ----
    float acc[4][4];
#pragma unroll
    for (int i = 0; i < 4; i++)
#pragma unroll
        for (int j = 0; j < 4; j++) acc[i][j] = 0.f;
    for (int kt = 0; kt < 12; kt++) {
        int kg = kt * 16;
        float4 cv = make_float4(0.f, 0.f, 0.f, 0.f);
        if (lr < M_) cv = *(const float4*)&cb[(size_t)lr * C_ + kg + 4 * lq];
        float4 pv = *(const float4*)&xb[(size_t)lr * C_ + kg + 4 * lq];
        __syncthreads();
        Ac[4 * lq + 0][lr] = cv.x; Ac[4 * lq + 1][lr] = cv.y;
        Ac[4 * lq + 2][lr] = cv.z; Ac[4 * lq + 3][lr] = cv.w;
        Bp[4 * lq + 0][lr] = pv.x; Bp[4 * lq + 1][lr] = pv.y;
        Bp[4 * lq + 2][lr] = pv.z; Bp[4 * lq + 3][lr] = pv.w;
        __syncthreads();
#pragma unroll
        for (int kk = 0; kk < 16; kk++) {
            float4 a = *(const float4*)&Ac[kk][4 * ty];
            float4 bb = *(const float4*)&Bp[kk][4 * tx];
            acc[0][0] += a.x * bb.x; acc[0][1] += a.x * bb.y; acc[0][2] += a.x * bb.z; acc[0][3] += a.x * bb.w;
            acc[1][0] += a.y * bb.x; acc[1][1] += a.y * bb.y; acc[1][2] += a.y * bb.z; acc[1][3] += a.y * bb.w;
            acc[2][0] += a.z * bb.x; acc[2][1] += a.z * bb.y; acc[2][2] += a.z * bb.z; acc[2][3] += a.z * bb.w;
            acc[3][0] += a.w * bb.x; acc[3][1] += a.w * bb.y; acc[3][2] += a.w * bb.z; acc[3][3] += a.w * bb.w;
        }
    }
    float c2v[4];
#pragma unroll
    for (int i = 0; i < 4; i++) {
        int m = 4 * ty + i;
        c2v[i] = (m < M_) ? c2g[(size_t)b * M_ + m] : 0.f;
    }
#pragma unroll
    for (int i = 0; i < 4; i++) {
        int m = 4 * ty + i;
        if (m < M_) {
#pragma unroll
            for (int j = 0; j < 4; j++)
                lg[(4 * tx + j) * LSTR + m] = 2.f * acc[i][j] - c2v[i];
        }
    }
    __syncthreads();
    // ---- softmax (4-way parallel per row) ----
    {
        int p = tid & 63, prt = tid >> 6;
        int m0 = prt * 13;
        int m1 = (prt == 3) ? M_ : m0 + 13;
        float* row = &lg[p * LSTR];
        float mx = -1e30f;
        for (int m = m0; m < m1; m++) mx = fmaxf(mx, row[m]);
        sred[prt * 64 + p] = mx;
        __syncthreads();
        mx = fmaxf(fmaxf(sred[p], sred[64 + p]), fmaxf(sred[128 + p], sred[192 + p]));
        float s = 0.f;
        for (int m = m0; m < m1; m++) {
            float e = expf(row[m] - mx);
            row[m] = e;
            s += e;
        }
        __syncthreads();
        sred[prt * 64 + p] = s;
        __syncthreads();
        s = sred[p] + sred[64 + p] + sred[128 + p] + sred[192 + p];
        float inv = 1.f / s;
        for (int m = m0; m < m1; m++) row[m] *= inv;
    }
    __syncthreads();
    // ---- weight-sum partials ----
    if (tid < M_) {
        float s = 0.f;
        for (int p = 0; p < 64; p++) s += lg[p * LSTR + tid];
        wsp[((size_t)b * CH_ + blk) * M_ + tid] = s;
    }
    // ---- phase 2: part[m][c] = sum_p w[p][m] * x[p][c], contraction p in 4x16
    float* pb = part + ((size_t)b * CH_ + blk) * (size_t)(M_ * C_);
    int pp = tid >> 4;
    int cq = (tid & 15) * 4;
    for (int ct = 0; ct < 3; ct++) {
        float a2[4][4];
#pragma unroll
        for (int i = 0; i < 4; i++)
#pragma unroll
            for (int j = 0; j < 4; j++) a2[i][j] = 0.f;
        for (int pt = 0; pt < 4; pt++) {
            float4 xv4 = *(const float4*)&xb[(size_t)(pt * 16 + pp) * C_ + ct * 64 + cq];
            float aw[4];
#pragma unroll
            for (int j = 0; j < 4; j++) {
                int m = cq + j;
                aw[j] = (m < M_) ? lg[(pt * 16 + pp) * LSTR + m] : 0.f;
            }
            __syncthreads();
            Ac[pp][cq + 0] = aw[0]; Ac[pp][cq + 1] = aw[1];
            Ac[pp][cq + 2] = aw[2]; Ac[pp][cq + 3] = aw[3];
            Bp[pp][cq + 0] = xv4.x; Bp[pp][cq + 1] = xv4.y;
            Bp[pp][cq + 2] = xv4.z; Bp[pp][cq + 3] = xv4.w;
            __syncthreads();
#pragma unroll
            for (int kk = 0; kk < 16; kk++) {
                float4 a = *(const float4*)&Ac[kk][4 * ty];
                float4 bb = *(const float4*)&Bp[kk][4 * tx];
                a2[0][0] += a.x * bb.x; a2[0][1] += a.x * bb.y; a2[0][2] += a.x * bb.z; a2[0][3] += a.x * bb.w;
                a2[1][0] += a.y * bb.x; a2[1][1] += a.y * bb.y; a2[1][2] += a.y * bb.z; a2[1][3] += a.y * bb.w;
                a2[2][0] += a.z * bb.x; a2[2][1] += a.z * bb.y; a2[2][2] += a.z * bb.z; a2[2][3] += a.z * bb.w;
                a2[3][0] += a.w * bb.x; a2[3][1] += a.w * bb.y; a2[3][2] += a.w * bb.z; a2[3][3] += a.w * bb.w;
            }
        }
#pragma unroll
        for (int i = 0; i < 4; i++) {
            int m = 4 * ty + i;
            if (m < M_)
                *(float4*)&pb[(size_t)m * C_ + ct * 64 + 4 * tx] =
                    make_float4(a2[i][0], a2[i][1], a2[i][2], a2[i][3]);
        }
    }
    // ---- topk (last iteration only; lg still intact) ----
    if (do_topk) {
        __syncthreads();
        if (tid < 64) {
            float* row = &lg[tid * LSTR];
            int* nb = nn + ((size_t)b * N_ + p0 + tid) * TK_;
            for (int r = 0; r < TK_; r++) {
                float bv = -1.f;
                int bi = 0;
                for (int m = 0; m < M_; m++) {
                    float v = row[m];
                    if (v > bv) { bv = v; bi = m; }   // strict > : lowest index wins ties
                }
                nb[r] = bi;
                row[bi] = -1.f;
            }
        }
    }
}

__global__ __launch_bounds__(192) void k_upd_reduce(const float* __restrict__ part,
        const float* __restrict__ wsp, float* __restrict__ cent, float* __restrict__ c2,
        unsigned short* __restrict__ cent16) {
    int m = blockIdx.x, b = blockIdx.y, c = threadIdx.x;
    __shared__ float sws;
    __shared__ float red[3];
    if (c == 0) {
        float s = 0.f;
        for (int ch = 0; ch < CH_; ch++) s += wsp[((size_t)b * CH_ + ch) * M_ + m];
        sws = s + 1e-8f;
    }
    float s = 0.f;
    for (int ch = 0; ch < CH_; ch++)
        s += part[(((size_t)b * CH_ + ch) * M_ + m) * (size_t)C_ + c];
    __syncthreads();
    float v = s / sws;
    size_t o = ((size_t)b * M_ + m) * C_ + c;
    cent[o] = v;
    cent16[o] = f2b(v);
    float q = v * v;
#pragma unroll
    for (int off = 32; off > 0; off >>= 1) q += __shfl_down(q, off, 64);
    if ((c & 63) == 0) red[c >> 6] = q;
    __syncthreads();
    if (c == 0) c2[(size_t)b * M_ + m] = red[0] + red[1] + red[2];
}

// ---------------- gathers (bf16 sources): edge max-rel + topk-centroid max ---
__global__ __launch_bounds__(192) void k_gather(const unsigned short* __restrict__ xt16,
        const unsigned short* __restrict__ cent16, const int* __restrict__ edge,
        const int* __restrict__ nn, unsigned short* __restrict__ xjt16,
        unsigned short* __restrict__ xjct16) {
    __shared__ int sidx[2 * K_ + TK_];
    int p = blockIdx.x, b = blockIdx.y, c = threadIdx.x;
    if (c < K_)
        sidx[c] = edge[((size_t)b * N_ + p) * K_ + c];
    else if (c < 2 * K_)
        sidx[c] = edge[(size_t)B_ * N_ * K_ + ((size_t)b * N_ + p) * K_ + (c - K_)];
    else if (c < 2 * K_ + TK_)
        sidx[c] = nn[((size_t)b * N_ + p) * TK_ + (c - 2 * K_)];
    __syncthreads();
    const unsigned short* xb = xt16 + (size_t)b * N_ * C_;
    const unsigned short* cbv = cent16 + (size_t)b * M_ * C_;
    float xv = b2f(xb[(size_t)p * C_ + c]);
    float mj = -1e30f;
#pragma unroll
    for (int kk = 0; kk < K_; kk++) {
        float vj = b2f(xb[(size_t)sidx[kk] * C_ + c]);
        float vi = b2f(xb[(size_t)sidx[K_ + kk] * C_ + c]);
        mj = fmaxf(mj, vj - vi);
    }
    float mc = -1e30f;
#pragma unroll
    for (int kk = 0; kk < TK_; kk++)
        mc = fmaxf(mc, b2f(cbv[(size_t)sidx[2 * K_ + kk] * C_ + c]));
    size_t o = ((size_t)b * N_ + p) * C_ + c;
    xjt16[o] = f2b(mj);
    xjct16[o] = f2b(mc - xv);
}

// ------- final conv via bf16 MFMA: full-OC 192(o) x 64(p) tile, feat read once
__global__ __launch_bounds__(256) void k_gemm(const unsigned short* __restrict__ Wg16,
        const unsigned short* __restrict__ xt16, const unsigned short* __restrict__ xjt16,
        const unsigned short* __restrict__ xjct16, const float* __restrict__ bias,
        float* __restrict__ out) {
    __shared__ short As[192 * GSTR];   // Wg k-chunk [o][32k]
    __shared__ short Bs[64 * GSTR];    // feat k-chunk [p][32k]
    int b = blockIdx.y;
    int po = blockIdx.x * 64;
    int tid = threadIdx.x;
    int wave = tid >> 6, lane = tid & 63;
    int m16 = lane & 15, q = lane >> 4;
    const unsigned short* s0 = xt16 + (size_t)b * N_ * C_;
    const unsigned short* s1 = xjt16 + (size_t)b * N_ * C_;
    const unsigned short* s2 = xjct16 + (size_t)b * N_ * C_;
    f32x4 acc[12];
#pragma unroll
    for (int i = 0; i < 12; i++) acc[i] = (f32x4){0.f, 0.f, 0.f, 0.f};
    int brow = tid >> 2, bch = tid & 3;
    for (int kt = 0; kt < 18; kt++) {
        int kg = kt * 32;
        int prt = kg / C_, koff = kg - prt * C_;
        const unsigned short* src = (prt == 0) ? s0 : ((prt == 1) ? s1 : s2);
        int4 av[3];
#pragma unroll
        for (int t = 0; t < 3; t++) {
            int idx = t * 256 + tid;
            av[t] = *(const int4*)&Wg16[(size_t)(idx >> 2) * KC_ + kg + (idx & 3) * 8];
        }
        int4 bv = *(const int4*)&src[(size_t)(po + brow) * C_ + koff + bch * 8];
        __syncthreads();
#pragma unroll
        for (int t = 0; t < 3; t++) {
            int idx = t * 256 + tid;
            *(int4*)&As[(idx >> 2) * GSTR + (idx & 3) * 8] = av[t];
        }
        *(int4*)&Bs[brow * GSTR + bch * 8] = bv;
        __syncthreads();
        b16x8 bf = *(const b16x8*)&Bs[(wave * 16 + m16) * GSTR + q * 8];
#pragma unroll
        for (int of = 0; of < 12; of++) {
            b16x8 af = *(const b16x8*)&As[(of * 16 + m16) * GSTR + q * 8];
            acc[of] = __builtin_amdgcn_mfma_f32_16x16x32_bf16(af, bf, acc[of], 0, 0, 0);
        }
    }
    int p = po + wave * 16 + m16;
#pragma unroll
    for (int of = 0; of < 12; of++) {
        int o = of * 16 + q * 4;
        float4 bv = *(const float4*)&bias[o];
        float bia[4] = {bv.x, bv.y, bv.z, bv.w};
#pragma unroll
        for (int r = 0; r < 4; r++)
            out[((size_t)b * OC_ + o + r) * N_ + p] = fmaxf(acc[of][r] + bia[r], 0.f);
    }
}

extern "C" void kernel_launch(void* const* d_in, const int* in_sizes, int n_in,
                              void* d_out, int out_size, void* d_ws, size_t ws_size,
                              hipStream_t stream) {
    (void)in_sizes; (void)n_in; (void)out_size; (void)ws_size;
    const float* x   = (const float*)d_in[0];
    const int* edge  = (const int*)d_in[1];
    const float* cw  = (const float*)d_in[2];
    const float* cbi = (const float*)d_in[3];
    float* ws = (float*)d_ws;
    size_t o = 0;
    float* xt   = ws + o; o += (size_t)B_ * N_ * C_;
    unsigned short* xt16 = (unsigned short*)(ws + o); o += (size_t)B_ * N_ * C_ / 2;
    unsigned short* Wg16 = (unsigned short*)(ws + o); o += (size_t)OC_ * KC_ / 2;
    float* cent = ws + o; o += (size_t)B_ * M_ * C_;
    unsigned short* cent16 = (unsigned short*)(ws + o); o += (size_t)B_ * M_ * C_ / 2;
    float* c2   = ws + o; o += (size_t)B_ * M_;
    float* part = ws + o; o += (size_t)B_ * CH_ * M_ * C_;
    float* wsp  = ws + o; o += (size_t)B_ * CH_ * M_;
    int* nn = (int*)(ws + o); o += (size_t)B_ * N_ * TK_;
    unsigned short* xjt16  = (unsigned short*)(ws + o); o += (size_t)B_ * N_ * C_ / 2;
    unsigned short* xjct16 = (unsigned short*)(ws + o); o += (size_t)B_ * N_ * C_ / 2;
    float* outp = (float*)d_out;

    k_rearrange_w<<<dim3(432), dim3(256), 0, stream>>>(cw, Wg16);
    k_transpose<<<dim3(N_ / 32, C_ / 32, B_), dim3(32, 8), 0, stream>>>(x, xt, xt16);
    k_init_cent<<<dim3(M_, B_), dim3(192), 0, stream>>>(xt, cent, c2);
    for (int it = 0; it < 3; it++) {
        k_logits_upd<<<dim3(CH_, B_), dim3(256), 0, stream>>>(xt, cent, c2, part, wsp, nn, (it == 2) ? 1 : 0);
        k_upd_reduce<<<dim3(M_, B_), dim3(192), 0, stream>>>(part, wsp, cent, c2, cent16);
    }
    k_gather<<<dim3(N_, B_), dim3(192), 0, stream>>>(xt16, cent16, edge, nn, xjt16, xjct16);
    k_gemm<<<dim3(N_ / 64, B_), dim3(256), 0, stream>>>(Wg16, xt16, xjt16, xjct16, cbi, outp);
}

// Round 5
// 376.904 us; speedup vs baseline: 1.6080x; 1.6080x over previous
//
#include <hip/hip_runtime.h>
#include <hip/hip_bf16.h>
#include <math.h>

#define B_   4
#define C_   192
#define N_   6400
#define K_   9
#define M_   50
#define TK_  12
#define OC_  192
#define KC_  576     // 3*C
#define CH_  50      // n-chunks for centroid update (128 points each)
#define PCH  128     // points per upd_partial chunk
#define MS_  25      // m-slice per upd_partial block
#define LSTR 53      // padded lg row stride (fp32; odd -> conflict-free)
#define GSTR 40      // bf16 LDS row stride (80 B, 16B-aligned, 2-way -> free)

typedef __bf16 b16x8 __attribute__((ext_vector_type(8)));
typedef float f32x4 __attribute__((ext_vector_type(4)));

__device__ inline unsigned short f2b(float f) {
    union { __hip_bfloat16 h; unsigned short u; } v;
    v.h = __float2bfloat16(f);
    return v.u;
}
__device__ inline float b2f(unsigned short u) {
    union { float f; unsigned int i; } v;
    v.i = ((unsigned int)u) << 16;
    return v.f;
}

// ---------------- W re-permute -> bf16: Wg16[o][t*192+ch] = conv_w[o][ch*3+t]
__global__ void k_rearrange_w(const float* __restrict__ cw, unsigned short* __restrict__ Wg16) {
    int g = blockIdx.x * 256 + threadIdx.x;           // < 192*576
    int o = g / KC_, r = g % KC_;
    int t = r / C_, ch = r % C_;
    Wg16[g] = f2b(cw[o * KC_ + ch * 3 + t]);
}

// ---------------- transpose x (b,c,n) -> xt fp32 + xt16 bf16 (b,n,c) ---------
__global__ void k_transpose(const float* __restrict__ x, float* __restrict__ xt,
                            unsigned short* __restrict__ xt16) {
    __shared__ float tile[32][33];
    int b = blockIdx.z;
    int p0 = blockIdx.x * 32, c0 = blockIdx.y * 32;
    int tx = threadIdx.x, ty = threadIdx.y;
    const float* xb = x + (size_t)b * C_ * N_;
    float* xtb = xt + (size_t)b * N_ * C_;
    unsigned short* xt16b = xt16 + (size_t)b * N_ * C_;
#pragma unroll
    for (int i = 0; i < 4; i++) {
        int cc = ty + 8 * i;
        tile[cc][tx] = xb[(size_t)(c0 + cc) * N_ + p0 + tx];
    }
    __syncthreads();
#pragma unroll
    for (int i = 0; i < 4; i++) {
        int pp = ty + 8 * i;
        float v = tile[tx][pp];
        size_t o = (size_t)(p0 + pp) * C_ + c0 + tx;
        xtb[o] = v;
        xt16b[o] = f2b(v);
    }
}

// ---------------- initial centroids: 5x10 adaptive avg pool (+ |c|^2) --------
__global__ __launch_bounds__(192) void k_init_cent(const float* __restrict__ xt,
        float* __restrict__ cent, float* __restrict__ c2) {
    int m = blockIdx.x, b = blockIdx.y, c = threadIdx.x;
    int gy = m / 10, gx = m % 10;
    const float* xtb = xt + (size_t)b * N_ * C_;
    float s = 0.f;
    for (int yy = 0; yy < 16; yy++)
        for (int xx = 0; xx < 8; xx++) {
            int p = (gy * 16 + yy) * 80 + gx * 8 + xx;
            s += xtb[(size_t)p * C_ + c];
        }
    float v = s * (1.f / 128.f);
    cent[((size_t)b * M_ + m) * C_ + c] = v;
    float q = v * v;
    __shared__ float red[3];
#pragma unroll
    for (int off = 32; off > 0; off >>= 1) q += __shfl_down(q, off, 64);
    if ((c & 63) == 0) red[c >> 6] = q;
    __syncthreads();
    if (c == 0) c2[(size_t)b * M_ + m] = red[0] + red[1] + red[2];
}

// ---------------- logits GEMM + softmax -> wt[b][m][n] (+ topk last iter) ----
__global__ __launch_bounds__(256) void k_logits(const float* __restrict__ xt,
        const float* __restrict__ cent, const float* __restrict__ c2g,
        float* __restrict__ wt, int* __restrict__ nn, int do_topk) {
    __shared__ float Ac[16][68];
    __shared__ float Bp[16][68];
    __shared__ float lg[64 * LSTR];
    __shared__ float sred[256];
    int b = blockIdx.y;
    int p0 = blockIdx.x * 64;
    int tid = threadIdx.x;
    int tx = tid & 15, ty = tid >> 4;
    int lr = tid >> 2, lq = tid & 3;
    const float* cb = cent + (size_t)b * M_ * C_;
    const float* xb = xt + ((size_t)b * N_ + p0) * C_;
    float acc[4][4];
#pragma unroll
    for (int i = 0; i < 4; i++)
#pragma unroll
        for (int j = 0; j < 4; j++) acc[i][j] = 0.f;
    for (int kt = 0; kt < 12; kt++) {
        int kg = kt * 16;
        float4 cv = make_float4(0.f, 0.f, 0.f, 0.f);
        if (lr < M_) cv = *(const float4*)&cb[(size_t)lr * C_ + kg + 4 * lq];
        float4 pv = *(const float4*)&xb[(size_t)lr * C_ + kg + 4 * lq];
        __syncthreads();
        Ac[4 * lq + 0][lr] = cv.x; Ac[4 * lq + 1][lr] = cv.y;
        Ac[4 * lq + 2][lr] = cv.z; Ac[4 * lq + 3][lr] = cv.w;
        Bp[4 * lq + 0][lr] = pv.x; Bp[4 * lq + 1][lr] = pv.y;
        Bp[4 * lq + 2][lr] = pv.z; Bp[4 * lq + 3][lr] = pv.w;
        __syncthreads();
#pragma unroll
        for (int kk = 0; kk < 16; kk++) {
            float4 a = *(const float4*)&Ac[kk][4 * ty];
            float4 bb = *(const float4*)&Bp[kk][4 * tx];
            acc[0][0] += a.x * bb.x; acc[0][1] += a.x * bb.y; acc[0][2] += a.x * bb.z; acc[0][3] += a.x * bb.w;
            acc[1][0] += a.y * bb.x; acc[1][1] += a.y * bb.y; acc[1][2] += a.y * bb.z; acc[1][3] += a.y * bb.w;
            acc[2][0] += a.z * bb.x; acc[2][1] += a.z * bb.y; acc[2][2] += a.z * bb.z; acc[2][3] += a.z * bb.w;
            acc[3][0] += a.w * bb.x; acc[3][1] += a.w * bb.y; acc[3][2] += a.w * bb.z; acc[3][3] += a.w * bb.w;
        }
    }
    float c2v[4];
#pragma unroll
    for (int i = 0; i < 4; i++) {
        int m = 4 * ty + i;
        c2v[i] = (m < M_) ? c2g[(size_t)b * M_ + m] : 0.f;
    }
#pragma unroll
    for (int i = 0; i < 4; i++) {
        int m = 4 * ty + i;
        if (m < M_) {
#pragma unroll
            for (int j = 0; j < 4; j++)
                lg[(4 * tx + j) * LSTR + m] = 2.f * acc[i][j] - c2v[i];
        }
    }
    __syncthreads();
    // 4-way parallel softmax per row
    {
        int p = tid & 63, prt = tid >> 6;
        int m0 = prt * 13;
        int m1 = (prt == 3) ? M_ : m0 + 13;
        float* row = &lg[p * LSTR];
        float mx = -1e30f;
        for (int m = m0; m < m1; m++) mx = fmaxf(mx, row[m]);
        sred[prt * 64 + p] = mx;
        __syncthreads();
        mx = fmaxf(fmaxf(sred[p], sred[64 + p]), fmaxf(sred[128 + p], sred[192 + p]));
        float s = 0.f;
        for (int m = m0; m < m1; m++) {
            float e = expf(row[m] - mx);
            row[m] = e;
            s += e;
        }
        __syncthreads();
        sred[prt * 64 + p] = s;
        __syncthreads();
        s = sred[p] + sred[64 + p] + sred[128 + p] + sred[192 + p];
        float inv = 1.f / s;
        for (int m = m0; m < m1; m++) row[m] *= inv;
    }
    __syncthreads();
    // store weights transposed: wt[b][m][p]  (contiguous 64-float runs per m)
    float* wtb = wt + (size_t)b * M_ * N_ + p0;
    for (int j = tid; j < 64 * M_; j += 256) {
        int m = j >> 6, p = j & 63;
        wtb[(size_t)m * N_ + p] = lg[p * LSTR + m];
    }
    if (do_topk) {
        __syncthreads();
        if (tid < 64) {
            float* row = &lg[tid * LSTR];
            int* nb = nn + ((size_t)b * N_ + p0 + tid) * TK_;
            for (int r = 0; r < TK_; r++) {
                float bv = -1.f;
                int bi = 0;
                for (int m = 0; m < M_; m++) {
                    float v = row[m];
                    if (v > bv) { bv = v; bi = m; }   // strict > : lowest index wins ties
                }
                nb[r] = bi;
                row[bi] = -1.f;
            }
        }
    }
}

// ---------------- centroid update: per-chunk, per-m-slice partial sums -------
__global__ __launch_bounds__(192) void k_upd_partial(const float* __restrict__ xt,
        const float* __restrict__ wt, float* __restrict__ part, float* __restrict__ wsp) {
    __shared__ float wl[MS_ * PCH];   // [mm][p]
    int ch = blockIdx.x, mh = blockIdx.y, b = blockIdx.z, c = threadIdx.x;
    int m0 = mh * MS_;
    int p0 = ch * PCH;
    for (int j = c; j < MS_ * PCH; j += 192) {
        int mm = j / PCH, p = j - mm * PCH;
        wl[j] = wt[((size_t)b * M_ + m0 + mm) * N_ + p0 + p];
    }
    __syncthreads();
    float acc[MS_];
#pragma unroll
    for (int mm = 0; mm < MS_; mm++) acc[mm] = 0.f;
    const float* xb = xt + ((size_t)b * N_ + p0) * C_;
    for (int p = 0; p < PCH; p++) {
        float xv = xb[(size_t)p * C_ + c];
#pragma unroll
        for (int mm = 0; mm < MS_; mm++) acc[mm] += wl[mm * PCH + p] * xv;  // LDS broadcast
    }
    float* pb = part + (((size_t)b * CH_ + ch) * M_ + m0) * (size_t)C_;
#pragma unroll
    for (int mm = 0; mm < MS_; mm++) pb[(size_t)mm * C_ + c] = acc[mm];
    if (c < MS_) {
        float s = 0.f;
        for (int p = 0; p < PCH; p++) s += wl[c * PCH + p];
        wsp[((size_t)b * CH_ + ch) * M_ + m0 + c] = s;
    }
}

__global__ __launch_bounds__(192) void k_upd_reduce(const float* __restrict__ part,
        const float* __restrict__ wsp, float* __restrict__ cent, float* __restrict__ c2,
        unsigned short* __restrict__ cent16) {
    int m = blockIdx.x, b = blockIdx.y, c = threadIdx.x;
    __shared__ float sws;
    __shared__ float red[3];
    if (c == 0) {
        float s = 0.f;
        for (int ch = 0; ch < CH_; ch++) s += wsp[((size_t)b * CH_ + ch) * M_ + m];
        sws = s + 1e-8f;
    }
    float s = 0.f;
    for (int ch = 0; ch < CH_; ch++)
        s += part[(((size_t)b * CH_ + ch) * M_ + m) * (size_t)C_ + c];
    __syncthreads();
    float v = s / sws;
    size_t o = ((size_t)b * M_ + m) * C_ + c;
    cent[o] = v;
    cent16[o] = f2b(v);
    float q = v * v;
#pragma unroll
    for (int off = 32; off > 0; off >>= 1) q += __shfl_down(q, off, 64);
    if ((c & 63) == 0) red[c >> 6] = q;
    __syncthreads();
    if (c == 0) c2[(size_t)b * M_ + m] = red[0] + red[1] + red[2];
}

// ---------------- gathers (bf16 sources): edge max-rel + topk-centroid max ---
__global__ __launch_bounds__(192) void k_gather(const unsigned short* __restrict__ xt16,
        const unsigned short* __restrict__ cent16, const int* __restrict__ edge,
        const int* __restrict__ nn, unsigned short* __restrict__ xjt16,
        unsigned short* __restrict__ xjct16) {
    __shared__ int sidx[2 * K_ + TK_];
    int p = blockIdx.x, b = blockIdx.y, c = threadIdx.x;
    if (c < K_)
        sidx[c] = edge[((size_t)b * N_ + p) * K_ + c];
    else if (c < 2 * K_)
        sidx[c] = edge[(size_t)B_ * N_ * K_ + ((size_t)b * N_ + p) * K_ + (c - K_)];
    else if (c < 2 * K_ + TK_)
        sidx[c] = nn[((size_t)b * N_ + p) * TK_ + (c - 2 * K_)];
    __syncthreads();
    const unsigned short* xb = xt16 + (size_t)b * N_ * C_;
    const unsigned short* cbv = cent16 + (size_t)b * M_ * C_;
    float xv = b2f(xb[(size_t)p * C_ + c]);
    float mj = -1e30f;
#pragma unroll
    for (int kk = 0; kk < K_; kk++) {
        float vj = b2f(xb[(size_t)sidx[kk] * C_ + c]);
        float vi = b2f(xb[(size_t)sidx[K_ + kk] * C_ + c]);
        mj = fmaxf(mj, vj - vi);
    }
    float mc = -1e30f;
#pragma unroll
    for (int kk = 0; kk < TK_; kk++)
        mc = fmaxf(mc, b2f(cbv[(size_t)sidx[2 * K_ + kk] * C_ + c]));
    size_t o = ((size_t)b * N_ + p) * C_ + c;
    xjt16[o] = f2b(mj);
    xjct16[o] = f2b(mc - xv);
}

// ------- final conv via bf16 MFMA: full-OC 192(o) x 64(p) tile, feat read once
__global__ __launch_bounds__(256) void k_gemm(const unsigned short* __restrict__ Wg16,
        const unsigned short* __restrict__ xt16, const unsigned short* __restrict__ xjt16,
        const unsigned short* __restrict__ xjct16, const float* __restrict__ bias,
        float* __restrict__ out) {
    __shared__ short As[192 * GSTR];   // Wg k-chunk [o][32k]
    __shared__ short Bs[64 * GSTR];    // feat k-chunk [p][32k]
    int b = blockIdx.y;
    int po = blockIdx.x * 64;
    int tid = threadIdx.x;
    int wave = tid >> 6, lane = tid & 63;
    int m16 = lane & 15, q = lane >> 4;
    const unsigned short* s0 = xt16 + (size_t)b * N_ * C_;
    const unsigned short* s1 = xjt16 + (size_t)b * N_ * C_;
    const unsigned short* s2 = xjct16 + (size_t)b * N_ * C_;
    f32x4 acc[12];
#pragma unroll
    for (int i = 0; i < 12; i++) acc[i] = (f32x4){0.f, 0.f, 0.f, 0.f};
    int brow = tid >> 2, bch = tid & 3;
    for (int kt = 0; kt < 18; kt++) {
        int kg = kt * 32;
        int prt = kg / C_, koff = kg - prt * C_;
        const unsigned short* src = (prt == 0) ? s0 : ((prt == 1) ? s1 : s2);
        int4 av[3];
#pragma unroll
        for (int t = 0; t < 3; t++) {
            int idx = t * 256 + tid;
            av[t] = *(const int4*)&Wg16[(size_t)(idx >> 2) * KC_ + kg + (idx & 3) * 8];
        }
        int4 bv = *(const int4*)&src[(size_t)(po + brow) * C_ + koff + bch * 8];
        __syncthreads();
#pragma unroll
        for (int t = 0; t < 3; t++) {
            int idx = t * 256 + tid;
            *(int4*)&As[(idx >> 2) * GSTR + (idx & 3) * 8] = av[t];
        }
        *(int4*)&Bs[brow * GSTR + bch * 8] = bv;
        __syncthreads();
        b16x8 bf = *(const b16x8*)&Bs[(wave * 16 + m16) * GSTR + q * 8];
#pragma unroll
        for (int of = 0; of < 12; of++) {
            b16x8 af = *(const b16x8*)&As[(of * 16 + m16) * GSTR + q * 8];
            acc[of] = __builtin_amdgcn_mfma_f32_16x16x32_bf16(af, bf, acc[of], 0, 0, 0);
        }
    }
    int p = po + wave * 16 + m16;
#pragma unroll
    for (int of = 0; of < 12; of++) {
        int o = of * 16 + q * 4;
        float4 bv = *(const float4*)&bias[o];
        float bia[4] = {bv.x, bv.y, bv.z, bv.w};
#pragma unroll
        for (int r = 0; r < 4; r++)
            out[((size_t)b * OC_ + o + r) * N_ + p] = fmaxf(acc[of][r] + bia[r], 0.f);
    }
}

extern "C" void kernel_launch(void* const* d_in, const int* in_sizes, int n_in,
                              void* d_out, int out_size, void* d_ws, size_t ws_size,
                              hipStream_t stream) {
    (void)in_sizes; (void)n_in; (void)out_size; (void)ws_size;
    const float* x   = (const float*)d_in[0];
    const int* edge  = (const int*)d_in[1];
    const float* cw  = (const float*)d_in[2];
    const float* cbi = (const float*)d_in[3];
    float* ws = (float*)d_ws;
    size_t o = 0;
    float* xt   = ws + o; o += (size_t)B_ * N_ * C_;
    unsigned short* xt16 = (unsigned short*)(ws + o); o += (size_t)B_ * N_ * C_ / 2;
    unsigned short* Wg16 = (unsigned short*)(ws + o); o += (size_t)OC_ * KC_ / 2;
    float* cent = ws + o; o += (size_t)B_ * M_ * C_;
    unsigned short* cent16 = (unsigned short*)(ws + o); o += (size_t)B_ * M_ * C_ / 2;
    float* c2   = ws + o; o += (size_t)B_ * M_;
    float* wt   = ws + o; o += (size_t)B_ * M_ * N_;
    float* part = ws + o; o += (size_t)B_ * CH_ * M_ * C_;
    float* wsp  = ws + o; o += (size_t)B_ * CH_ * M_;
    int* nn = (int*)(ws + o); o += (size_t)B_ * N_ * TK_;
    unsigned short* xjt16  = (unsigned short*)(ws + o); o += (size_t)B_ * N_ * C_ / 2;
    unsigned short* xjct16 = (unsigned short*)(ws + o); o += (size_t)B_ * N_ * C_ / 2;
    float* outp = (float*)d_out;

    k_rearrange_w<<<dim3(432), dim3(256), 0, stream>>>(cw, Wg16);
    k_transpose<<<dim3(N_ / 32, C_ / 32, B_), dim3(32, 8), 0, stream>>>(x, xt, xt16);
    k_init_cent<<<dim3(M_, B_), dim3(192), 0, stream>>>(xt, cent, c2);
    for (int it = 0; it < 3; it++) {
        k_logits<<<dim3(N_ / 64, B_), dim3(256), 0, stream>>>(xt, cent, c2, wt, nn, (it == 2) ? 1 : 0);
        k_upd_partial<<<dim3(CH_, 2, B_), dim3(192), 0, stream>>>(xt, wt, part, wsp);
        k_upd_reduce<<<dim3(M_, B_), dim3(192), 0, stream>>>(part, wsp, cent, c2, cent16);
    }
    k_gather<<<dim3(N_, B_), dim3(192), 0, stream>>>(xt16, cent16, edge, nn, xjt16, xjct16);
    k_gemm<<<dim3(N_ / 64, B_), dim3(256), 0, stream>>>(Wg16, xt16, xjt16, xjct16, cbi, outp);
}

// Round 7
// 339.436 us; speedup vs baseline: 1.7855x; 1.1104x over previous
//
#include <hip/hip_runtime.h>
#include <hip/hip_bf16.h>
#include <math.h>

#define B_   4
#define C_   192
#define N_   6400
#define K_   9
#define M_   50
#define TK_  12
#define OC_  192
#define KC_  576     // 3*C
#define CH_  100     // 64-point chunks per batch
#define LSTR 53      // padded lg row stride (fp32; odd -> conflict-free)
#define GSTR 40      // bf16 LDS row stride (80 B, 16B-aligned, 2-way -> free)

typedef __bf16 b16x8 __attribute__((ext_vector_type(8)));
typedef float f32x4 __attribute__((ext_vector_type(4)));

__device__ inline unsigned short f2b(float f) {
    union { __hip_bfloat16 h; unsigned short u; } v;
    v.h = __float2bfloat16(f);
    return v.u;
}
__device__ inline float b2f(unsigned short u) {
    union { float f; unsigned int i; } v;
    v.i = ((unsigned int)u) << 16;
    return v.f;
}

// ---------------- W re-permute -> bf16: Wg16[o][t*192+ch] = conv_w[o][ch*3+t]
__global__ void k_rearrange_w(const float* __restrict__ cw, unsigned short* __restrict__ Wg16) {
    int g = blockIdx.x * 256 + threadIdx.x;           // < 192*576
    int o = g / KC_, r = g % KC_;
    int t = r / C_, ch = r % C_;
    Wg16[g] = f2b(cw[o * KC_ + ch * 3 + t]);
}

// ---------------- transpose x (b,c,n) -> xt fp32 + xt16 bf16 (b,n,c) ---------
__global__ void k_transpose(const float* __restrict__ x, float* __restrict__ xt,
                            unsigned short* __restrict__ xt16) {
    __shared__ float tile[32][33];
    int b = blockIdx.z;
    int p0 = blockIdx.x * 32, c0 = blockIdx.y * 32;
    int tx = threadIdx.x, ty = threadIdx.y;
    const float* xb = x + (size_t)b * C_ * N_;
    float* xtb = xt + (size_t)b * N_ * C_;
    unsigned short* xt16b = xt16 + (size_t)b * N_ * C_;
#pragma unroll
    for (int i = 0; i < 4; i++) {
        int cc = ty + 8 * i;
        tile[cc][tx] = xb[(size_t)(c0 + cc) * N_ + p0 + tx];
    }
    __syncthreads();
#pragma unroll
    for (int i = 0; i < 4; i++) {
        int pp = ty + 8 * i;
        float v = tile[tx][pp];
        size_t o = (size_t)(p0 + pp) * C_ + c0 + tx;
        xtb[o] = v;
        xt16b[o] = f2b(v);
    }
}

// ---------------- initial centroids: 5x10 adaptive avg pool (+ |c|^2) --------
__global__ __launch_bounds__(192) void k_init_cent(const float* __restrict__ xt,
        float* __restrict__ cent, float* __restrict__ c2) {
    int m = blockIdx.x, b = blockIdx.y, c = threadIdx.x;
    int gy = m / 10, gx = m % 10;
    const float* xtb = xt + (size_t)b * N_ * C_;
    float s = 0.f;
    for (int yy = 0; yy < 16; yy++)
        for (int xx = 0; xx < 8; xx++) {
            int p = (gy * 16 + yy) * 80 + gx * 8 + xx;
            s += xtb[(size_t)p * C_ + c];
        }
    float v = s * (1.f / 128.f);
    cent[((size_t)b * M_ + m) * C_ + c] = v;
    float q = v * v;
    __shared__ float red[3];
#pragma unroll
    for (int off = 32; off > 0; off >>= 1) q += __shfl_down(q, off, 64);
    if ((c & 63) == 0) red[c >> 6] = q;
    __syncthreads();
    if (c == 0) c2[(size_t)b * M_ + m] = red[0] + red[1] + red[2];
}

// ==== fused: logits GEMM + softmax + local partial sums (+ topk last iter) ===
// phase 1: lg[p][m] = softmax_m(2*x.c - |c|^2)   (64 p x 50 m, K=192)
// phase 2: part[m][c] = sum_p lg[p][m]*x[p][c]   (threads 0..191: acc[50],
//          x prefetched 16-deep in registers; lg broadcast ds_reads)
__global__ __launch_bounds__(256) void k_logits_upd(const float* __restrict__ xt,
        const float* __restrict__ cent, const float* __restrict__ c2g,
        float* __restrict__ part, float* __restrict__ wsp,
        int* __restrict__ nn, int do_topk) {
    __shared__ float Ac[16][68];
    __shared__ float Bp[16][68];
    __shared__ float lg[64 * LSTR];
    __shared__ float sred[256];
    int b = blockIdx.y;
    int blk = blockIdx.x;
    int p0 = blk * 64;
    int tid = threadIdx.x;
    int tx = tid & 15, ty = tid >> 4;
    int lr = tid >> 2, lq = tid & 3;
    const float* cb = cent + (size_t)b * M_ * C_;
    const float* xb = xt + ((size_t)b * N_ + p0) * C_;
    // ---- phase 1: logits GEMM ----
    {
        float acc[4][4];
#pragma unroll
        for (int i = 0; i < 4; i++)
#pragma unroll
            for (int j = 0; j < 4; j++) acc[i][j] = 0.f;
        for (int kt = 0; kt < 12; kt++) {
            int kg = kt * 16;
            float4 cv = make_float4(0.f, 0.f, 0.f, 0.f);
            if (lr < M_) cv = *(const float4*)&cb[(size_t)lr * C_ + kg + 4 * lq];
            float4 pv = *(const float4*)&xb[(size_t)lr * C_ + kg + 4 * lq];
            __syncthreads();
            Ac[4 * lq + 0][lr] = cv.x; Ac[4 * lq + 1][lr] = cv.y;
            Ac[4 * lq + 2][lr] = cv.z; Ac[4 * lq + 3][lr] = cv.w;
            Bp[4 * lq + 0][lr] = pv.x; Bp[4 * lq + 1][lr] = pv.y;
            Bp[4 * lq + 2][lr] = pv.z; Bp[4 * lq + 3][lr] = pv.w;
            __syncthreads();
#pragma unroll
            for (int kk = 0; kk < 16; kk++) {
                float4 a = *(const float4*)&Ac[kk][4 * ty];
                float4 bb = *(const float4*)&Bp[kk][4 * tx];
                acc[0][0] += a.x * bb.x; acc[0][1] += a.x * bb.y; acc[0][2] += a.x * bb.z; acc[0][3] += a.x * bb.w;
                acc[1][0] += a.y * bb.x; acc[1][1] += a.y * bb.y; acc[1][2] += a.y * bb.z; acc[1][3] += a.y * bb.w;
                acc[2][0] += a.z * bb.x; acc[2][1] += a.z * bb.y; acc[2][2] += a.z * bb.z; acc[2][3] += a.z * bb.w;
                acc[3][0] += a.w * bb.x; acc[3][1] += a.w * bb.y; acc[3][2] += a.w * bb.z; acc[3][3] += a.w * bb.w;
            }
        }
#pragma unroll
        for (int i = 0; i < 4; i++) {
            int m = 4 * ty + i;
            if (m < M_) {
                float c2v = c2g[(size_t)b * M_ + m];
#pragma unroll
                for (int j = 0; j < 4; j++)
                    lg[(4 * tx + j) * LSTR + m] = 2.f * acc[i][j] - c2v;
            }
        }
    }
    __syncthreads();
    // ---- softmax (4-way parallel per row) ----
    {
        int p = tid & 63, prt = tid >> 6;
        int m0 = prt * 13;
        int m1 = (prt == 3) ? M_ : m0 + 13;
        float* row = &lg[p * LSTR];
        float mx = -1e30f;
        for (int m = m0; m < m1; m++) mx = fmaxf(mx, row[m]);
        sred[prt * 64 + p] = mx;
        __syncthreads();
        mx = fmaxf(fmaxf(sred[p], sred[64 + p]), fmaxf(sred[128 + p], sred[192 + p]));
        float s = 0.f;
        for (int m = m0; m < m1; m++) {
            float e = expf(row[m] - mx);
            row[m] = e;
            s += e;
        }
        __syncthreads();
        sred[prt * 64 + p] = s;
        __syncthreads();
        s = sred[p] + sred[64 + p] + sred[128 + p] + sred[192 + p];
        float inv = 1.f / s;
        for (int m = m0; m < m1; m++) row[m] *= inv;
    }
    __syncthreads();
    // ---- phase 2: partials (lg read-only from here) ----
    if (tid < 192) {
        int c = tid;
        float acc[M_];
#pragma unroll
        for (int mm = 0; mm < M_; mm++) acc[mm] = 0.f;
        for (int pc = 0; pc < 4; pc++) {
            float xq[16];
#pragma unroll
            for (int i = 0; i < 16; i++)
                xq[i] = xb[(size_t)(pc * 16 + i) * C_ + c];   // 16 independent L2-hot loads
#pragma unroll
            for (int i = 0; i < 16; i++) {
                const float* row = &lg[(pc * 16 + i) * LSTR];
#pragma unroll
                for (int mm = 0; mm < M_; mm++)
                    acc[mm] += row[mm] * xq[i];               // broadcast ds_read_b128
            }
        }
        float* pb = part + ((size_t)b * CH_ + blk) * (size_t)(M_ * C_);
#pragma unroll
        for (int mm = 0; mm < M_; mm++) pb[(size_t)mm * C_ + c] = acc[mm];
    } else if (tid < 192 + M_) {
        int m = tid - 192;
        float s = 0.f;
        for (int p = 0; p < 64; p++) s += lg[p * LSTR + m];
        wsp[((size_t)b * CH_ + blk) * M_ + m] = s;
    }
    // ---- topk on last iteration (destroys lg; after phase-2 reads) ----
    if (do_topk) {
        __syncthreads();
        if (tid < 64) {
            float* row = &lg[tid * LSTR];
            int* nb = nn + ((size_t)b * N_ + p0 + tid) * TK_;
            for (int r = 0; r < TK_; r++) {
                float bv = -1.f;
                int bi = 0;
                for (int m = 0; m < M_; m++) {
                    float v = row[m];
                    if (v > bv) { bv = v; bi = m; }   // strict > : lowest index wins ties
                }
                nb[r] = bi;
                row[bi] = -1.f;
            }
        }
    }
}

__global__ __launch_bounds__(192) void k_upd_reduce(const float* __restrict__ part,
        const float* __restrict__ wsp, float* __restrict__ cent, float* __restrict__ c2,
        unsigned short* __restrict__ cent16, int last) {
    int m = blockIdx.x, b = blockIdx.y, c = threadIdx.x;
    __shared__ float sws;
    __shared__ float red[3];
    if (c == 0) {
        float s = 0.f;
        for (int ch = 0; ch < CH_; ch++) s += wsp[((size_t)b * CH_ + ch) * M_ + m];
        sws = s + 1e-8f;
    }
    float s = 0.f;
    for (int ch = 0; ch < CH_; ch++)
        s += part[(((size_t)b * CH_ + ch) * M_ + m) * (size_t)C_ + c];
    __syncthreads();
    float v = s / sws;
    size_t o = ((size_t)b * M_ + m) * C_ + c;
    cent[o] = v;
    if (last) cent16[o] = f2b(v);
    float q = v * v;
#pragma unroll
    for (int off = 32; off > 0; off >>= 1) q += __shfl_down(q, off, 64);
    if ((c & 63) == 0) red[c >> 6] = q;
    __syncthreads();
    if (c == 0) c2[(size_t)b * M_ + m] = red[0] + red[1] + red[2];
}

// ---------------- gathers (bf16 sources): edge max-rel + topk-centroid max ---
__global__ __launch_bounds__(192) void k_gather(const unsigned short* __restrict__ xt16,
        const unsigned short* __restrict__ cent16, const int* __restrict__ edge,
        const int* __restrict__ nn, unsigned short* __restrict__ xjt16,
        unsigned short* __restrict__ xjct16) {
    __shared__ int sidx[2 * K_ + TK_];
    int p = blockIdx.x, b = blockIdx.y, c = threadIdx.x;
    if (c < K_)
        sidx[c] = edge[((size_t)b * N_ + p) * K_ + c];
    else if (c < 2 * K_)
        sidx[c] = edge[(size_t)B_ * N_ * K_ + ((size_t)b * N_ + p) * K_ + (c - K_)];
    else if (c < 2 * K_ + TK_)
        sidx[c] = nn[((size_t)b * N_ + p) * TK_ + (c - 2 * K_)];
    __syncthreads();
    const unsigned short* xb = xt16 + (size_t)b * N_ * C_;
    const unsigned short* cbv = cent16 + (size_t)b * M_ * C_;
    float xv = b2f(xb[(size_t)p * C_ + c]);
    float mj = -1e30f;
#pragma unroll
    for (int kk = 0; kk < K_; kk++) {
        float vj = b2f(xb[(size_t)sidx[kk] * C_ + c]);
        float vi = b2f(xb[(size_t)sidx[K_ + kk] * C_ + c]);
        mj = fmaxf(mj, vj - vi);
    }
    float mc = -1e30f;
#pragma unroll
    for (int kk = 0; kk < TK_; kk++)
        mc = fmaxf(mc, b2f(cbv[(size_t)sidx[2 * K_ + kk] * C_ + c]));
    size_t o = ((size_t)b * N_ + p) * C_ + c;
    xjt16[o] = f2b(mj);
    xjct16[o] = f2b(mc - xv);
}

// ------- final conv via bf16 MFMA: full-OC 192(o) x 64(p) tile, feat read once
__global__ __launch_bounds__(256) void k_gemm(const unsigned short* __restrict__ Wg16,
        const unsigned short* __restrict__ xt16, const unsigned short* __restrict__ xjt16,
        const unsigned short* __restrict__ xjct16, const float* __restrict__ bias,
        float* __restrict__ out) {
    __shared__ short As[192 * GSTR];   // Wg k-chunk [o][32k]
    __shared__ short Bs[64 * GSTR];    // feat k-chunk [p][32k]
    int b = blockIdx.y;
    int po = blockIdx.x * 64;
    int tid = threadIdx.x;
    int wave = tid >> 6, lane = tid & 63;
    int m16 = lane & 15, q = lane >> 4;
    const unsigned short* s0 = xt16 + (size_t)b * N_ * C_;
    const unsigned short* s1 = xjt16 + (size_t)b * N_ * C_;
    const unsigned short* s2 = xjct16 + (size_t)b * N_ * C_;
    f32x4 acc[12];
#pragma unroll
    for (int i = 0; i < 12; i++) acc[i] = (f32x4){0.f, 0.f, 0.f, 0.f};
    int brow = tid >> 2, bch = tid & 3;
    for (int kt = 0; kt < 18; kt++) {
        int kg = kt * 32;
        int prt = kg / C_, koff = kg - prt * C_;
        const unsigned short* src = (prt == 0) ? s0 : ((prt == 1) ? s1 : s2);
        int4 av[3];
#pragma unroll
        for (int t = 0; t < 3; t++) {
            int idx = t * 256 + tid;
            av[t] = *(const int4*)&Wg16[(size_t)(idx >> 2) * KC_ + kg + (idx & 3) * 8];
        }
        int4 bv = *(const int4*)&src[(size_t)(po + brow) * C_ + koff + bch * 8];
        __syncthreads();
#pragma unroll
        for (int t = 0; t < 3; t++) {
            int idx = t * 256 + tid;
            *(int4*)&As[(idx >> 2) * GSTR + (idx & 3) * 8] = av[t];
        }
        *(int4*)&Bs[brow * GSTR + bch * 8] = bv;
        __syncthreads();
        b16x8 bf = *(const b16x8*)&Bs[(wave * 16 + m16) * GSTR + q * 8];
#pragma unroll
        for (int of = 0; of < 12; of++) {
            b16x8 af = *(const b16x8*)&As[(of * 16 + m16) * GSTR + q * 8];
            acc[of] = __builtin_amdgcn_mfma_f32_16x16x32_bf16(af, bf, acc[of], 0, 0, 0);
        }
    }
    int p = po + wave * 16 + m16;
#pragma unroll
    for (int of = 0; of < 12; of++) {
        int o = of * 16 + q * 4;
        float4 bv = *(const float4*)&bias[o];
        float bia[4] = {bv.x, bv.y, bv.z, bv.w};
#pragma unroll
        for (int r = 0; r < 4; r++)
            out[((size_t)b * OC_ + o + r) * N_ + p] = fmaxf(acc[of][r] + bia[r], 0.f);
    }
}

extern "C" void kernel_launch(void* const* d_in, const int* in_sizes, int n_in,
                              void* d_out, int out_size, void* d_ws, size_t ws_size,
                              hipStream_t stream) {
    (void)in_sizes; (void)n_in; (void)out_size; (void)ws_size;
    const float* x   = (const float*)d_in[0];
    const int* edge  = (const int*)d_in[1];
    const float* cw  = (const float*)d_in[2];
    const float* cbi = (const float*)d_in[3];
    float* ws = (float*)d_ws;
    size_t o = 0;
    float* xt   = ws + o; o += (size_t)B_ * N_ * C_;
    unsigned short* xt16 = (unsigned short*)(ws + o); o += (size_t)B_ * N_ * C_ / 2;
    unsigned short* Wg16 = (unsigned short*)(ws + o); o += (size_t)OC_ * KC_ / 2;
    float* cent = ws + o; o += (size_t)B_ * M_ * C_;
    unsigned short* cent16 = (unsigned short*)(ws + o); o += (size_t)B_ * M_ * C_ / 2;
    float* c2   = ws + o; o += (size_t)B_ * M_;
    float* part = ws + o; o += (size_t)B_ * CH_ * M_ * C_;
    float* wsp  = ws + o; o += (size_t)B_ * CH_ * M_;
    int* nn = (int*)(ws + o); o += (size_t)B_ * N_ * TK_;
    unsigned short* xjt16  = (unsigned short*)(ws + o); o += (size_t)B_ * N_ * C_ / 2;
    unsigned short* xjct16 = (unsigned short*)(ws + o); o += (size_t)B_ * N_ * C_ / 2;
    float* outp = (float*)d_out;

    k_rearrange_w<<<dim3(432), dim3(256), 0, stream>>>(cw, Wg16);
    k_transpose<<<dim3(N_ / 32, C_ / 32, B_), dim3(32, 8), 0, stream>>>(x, xt, xt16);
    k_init_cent<<<dim3(M_, B_), dim3(192), 0, stream>>>(xt, cent, c2);
    for (int it = 0; it < 3; it++) {
        k_logits_upd<<<dim3(CH_, B_), dim3(256), 0, stream>>>(xt, cent, c2, part, wsp, nn, (it == 2) ? 1 : 0);
        k_upd_reduce<<<dim3(M_, B_), dim3(192), 0, stream>>>(part, wsp, cent, c2, cent16, (it == 2) ? 1 : 0);
    }
    k_gather<<<dim3(N_, B_), dim3(192), 0, stream>>>(xt16, cent16, edge, nn, xjt16, xjct16);
    k_gemm<<<dim3(N_ / 64, B_), dim3(256), 0, stream>>>(Wg16, xt16, xjt16, xjct16, cbi, outp);
}